// Round 5
// baseline (257.827 us; speedup 1.0000x reference)
//
#include <hip/hip_runtime.h>

#define T_TOK 2048
#define DM    512
#define DFF   512
#define NE    16

typedef __attribute__((ext_vector_type(8))) short bf16x8;
typedef __attribute__((ext_vector_type(4))) float f32x4;
typedef __attribute__((ext_vector_type(8))) unsigned short us8;

__device__ __forceinline__ unsigned short f2bf(float f) {
  unsigned int u = __float_as_uint(f);
  u += 0x7fffu + ((u >> 16) & 1u);   // round-to-nearest-even
  return (unsigned short)(u >> 16);
}

#define MFMA(a,b,c) __builtin_amdgcn_mfma_f32_16x16x32_bf16((a),(b),(c),0,0,0)

// ---------------- prep: blocks 0..511 router, 512+ fp32->bf16 convert ------
__global__ __launch_bounds__(256) void prep_kernel(
    const float* __restrict__ x, const float* __restrict__ gw,
    const float* __restrict__ bias, int* __restrict__ counts,
    int* __restrict__ list, float* __restrict__ wgt,
    const float* __restrict__ sgu, const float* __restrict__ sdn,
    const float* __restrict__ egu, const float* __restrict__ edn,
    unsigned short* __restrict__ xb,   unsigned short* __restrict__ sgub,
    unsigned short* __restrict__ sdnb, unsigned short* __restrict__ egub,
    unsigned short* __restrict__ ednb)
{
  const int tid = threadIdx.x;
  if (blockIdx.x >= 512) {
    // convert: group = 8 elems. x 131072 | sgu 65536 | sdn 32768 | egu 1048576 | edn 524288
    int g = (blockIdx.x - 512) * 256 + tid;
    const float* s; unsigned short* d; int l;
    if      (g <  131072) { s = x;   d = xb;   l = g;           }
    else if (g <  196608) { s = sgu; d = sgub; l = g -  131072; }
    else if (g <  229376) { s = sdn; d = sdnb; l = g -  196608; }
    else if (g < 1277952) { s = egu; d = egub; l = g -  229376; }
    else                  { s = edn; d = ednb; l = g - 1277952; }
    const float* p = s + (size_t)l * 8;
    float4 v0 = *(const float4*)p;
    float4 v1 = *(const float4*)(p + 4);
    us8 o;
    o[0]=f2bf(v0.x); o[1]=f2bf(v0.y); o[2]=f2bf(v0.z); o[3]=f2bf(v0.w);
    o[4]=f2bf(v1.x); o[5]=f2bf(v1.y); o[6]=f2bf(v1.z); o[7]=f2bf(v1.w);
    *(us8*)(d + (size_t)l * 8) = o;
    return;
  }

  // ---- router: one token per wave ----
  __shared__ float lg[4][16];
  __shared__ int bcnt[16], bbase[16];
  __shared__ int sel_s[4][3], pos_s[4][3];
  __shared__ float g_s[4][3];

  const int w = tid >> 6, lane = tid & 63;
  if (tid < 16) bcnt[tid] = 0;
  const int tok = blockIdx.x * 4 + w;
  const int e = lane & 15, part = lane >> 4;

  const float* xr = x + (size_t)tok * DM + part * 128;
  const float* wr = gw + (size_t)e * DM + part * 128;
  float acc = 0.f;
  #pragma unroll 8
  for (int i = 0; i < 128; i += 4) {
    float4 xv = *(const float4*)(xr + i);
    float4 wv = *(const float4*)(wr + i);
    acc += xv.x*wv.x + xv.y*wv.y + xv.z*wv.z + xv.w*wv.w;
  }
  acc += __shfl_xor(acc, 16);
  acc += __shfl_xor(acc, 32);
  if (lane < 16) lg[w][lane] = 1.f / (1.f + __expf(-acc));  // affinity
  __syncthreads();

  if (tid < 4) {
    float aff[16], sc[16];
    #pragma unroll
    for (int i = 0; i < 16; ++i) { aff[i] = lg[tid][i]; sc[i] = aff[i] + bias[i]; }
    int sel[3]; float sa[3]; float sum = 0.f;
    #pragma unroll
    for (int k = 0; k < 3; ++k) {
      float best = -1e30f; int bi = 0;
      for (int i = 0; i < 16; ++i) {
        bool used = false;
        for (int j = 0; j < k; ++j) used |= (sel[j] == i);
        if (!used && sc[i] > best) { best = sc[i]; bi = i; }
      }
      sel[k] = bi; sa[k] = aff[bi]; sum += aff[bi];
    }
    float inv = 1.f / (sum + 1e-9f);
    #pragma unroll
    for (int k = 0; k < 3; ++k) {
      int p = atomicAdd(&bcnt[sel[k]], 1);
      sel_s[tid][k] = sel[k]; pos_s[tid][k] = p; g_s[tid][k] = sa[k] * inv;
    }
  }
  __syncthreads();
  if (tid < 16) bbase[tid] = atomicAdd(&counts[tid], bcnt[tid]);
  __syncthreads();
  if (tid < 4) {
    #pragma unroll
    for (int k = 0; k < 3; ++k) {
      int E = sel_s[tid][k];
      int p = bbase[E] + pos_s[tid][k];
      list[E * T_TOK + p] = blockIdx.x * 4 + tid;
      wgt [E * T_TOK + p] = g_s[tid][k];
    }
  }
}

// ---------------- GEMM1: LDS-free. 128 tok x 128 Hcols per block -----------
// 4 waves of 64x64; fragments loaded straight from global (L2/L3-resident).
// z=0 shared expert, z>=1 routed expert z-1. Fused silu(g)*u -> Hall (bf16).
__global__ __launch_bounds__(256) void gemm1_fused(
    const unsigned short* __restrict__ Xb, const unsigned short* __restrict__ Wsh,
    const unsigned short* __restrict__ Wex, unsigned short* __restrict__ Hall,
    const int* __restrict__ counts, const int* __restrict__ list)
{
  const int n0 = blockIdx.x * 128;          // H col block
  const int mt = blockIdx.y, z = blockIdx.z;
  int cnt, hb; const unsigned short* W;
  if (z == 0) { cnt = T_TOK; hb = 0; W = Wsh; }
  else {
    const int e = z - 1;
    cnt = counts[e];
    if (mt * 128 >= cnt) return;
    hb = T_TOK;
    for (int i = 0; i < e; ++i) hb += counts[i];
    W = Wex + (size_t)e * (2 * DFF * DM);
  }

  const int tid = threadIdx.x, w = tid >> 6;
  const int wm = (w & 1) * 64;       // wave row base
  const int wh = (w >> 1) * 64;      // wave H-col base
  const int lane = tid & 63, lr = lane & 15, qd = lane >> 4;

  // per-lane fragment base pointers (A rows gathered; rows >= cnt clamped)
  const unsigned short* ap[4];
  #pragma unroll
  for (int i = 0; i < 4; ++i) {
    int row = mt * 128 + wm + 16 * i + lr;
    int rc  = row < cnt ? row : cnt - 1;
    int tok = (z == 0) ? rc : list[(z - 1) * T_TOK + rc];
    ap[i] = Xb + (size_t)tok * DM + qd * 8;
  }
  const unsigned short *bg[4], *bu[4];
  #pragma unroll
  for (int j = 0; j < 4; ++j) {
    int col = n0 + wh + 16 * j + lr;
    bg[j] = W + (size_t)col * DM + qd * 8;
    bu[j] = W + (size_t)(DFF + col) * DM + qd * 8;
  }

  const f32x4 z4 = {0.f, 0.f, 0.f, 0.f};
  f32x4 accg[4][4], accu[4][4];
  #pragma unroll
  for (int i = 0; i < 4; ++i)
    #pragma unroll
    for (int j = 0; j < 4; ++j) { accg[i][j] = z4; accu[i][j] = z4; }

  #pragma unroll
  for (int k = 0; k < DM; k += 32) {       // one 16x16x32 MFMA step per iter
    bf16x8 a[4], g[4], u[4];
    #pragma unroll
    for (int i = 0; i < 4; ++i) a[i] = *(const bf16x8*)(ap[i] + k);
    #pragma unroll
    for (int j = 0; j < 4; ++j) { g[j] = *(const bf16x8*)(bg[j] + k);
                                  u[j] = *(const bf16x8*)(bu[j] + k); }
    #pragma unroll
    for (int j = 0; j < 4; ++j)
      #pragma unroll
      for (int i = 0; i < 4; ++i) {
        accg[i][j] = MFMA(a[i], g[j], accg[i][j]);
        accu[i][j] = MFMA(a[i], u[j], accu[i][j]);
      }
  }

  #pragma unroll
  for (int i = 0; i < 4; ++i) {
    #pragma unroll
    for (int r = 0; r < 4; ++r) {
      const int ent = mt * 128 + wm + 16 * i + qd * 4 + r;
      if (ent < cnt) {
        const size_t rowoff = (size_t)(hb + ent) * DFF + n0 + wh;
        #pragma unroll
        for (int j = 0; j < 4; ++j) {
          float gv = accg[i][j][r];
          float uv = accu[i][j][r];
          float h = (gv / (1.f + __expf(-gv))) * uv;   // silu(g)*u
          Hall[rowoff + 16 * j + lr] = f2bf(h);
        }
      }
    }
  }
}

// ---------------- GEMM2: LDS-free. 128 tok x 128 out-cols per block --------
__global__ __launch_bounds__(256) void gemm2_fused(
    const unsigned short* __restrict__ Hall, const unsigned short* __restrict__ Wsh,
    const unsigned short* __restrict__ Wex, float* __restrict__ out,
    const int* __restrict__ counts, const int* __restrict__ list,
    const float* __restrict__ wgt)
{
  const int n0 = blockIdx.x * 128;          // out col block
  const int mt = blockIdx.y, z = blockIdx.z;
  int cnt, hb; const unsigned short* W;
  if (z == 0) { cnt = T_TOK; hb = 0; W = Wsh; }
  else {
    const int e = z - 1;
    cnt = counts[e];
    if (mt * 128 >= cnt) return;
    hb = T_TOK;
    for (int i = 0; i < e; ++i) hb += counts[i];
    W = Wex + (size_t)e * (DM * DFF);
  }

  const int tid = threadIdx.x, w = tid >> 6;
  const int wm = (w & 1) * 64;
  const int wn = (w >> 1) * 64;
  const int lane = tid & 63, lr = lane & 15, qd = lane >> 4;

  const unsigned short* ap[4];
  #pragma unroll
  for (int i = 0; i < 4; ++i) {
    int row = mt * 128 + wm + 16 * i + lr;
    int rc  = row < cnt ? row : cnt - 1;
    ap[i] = Hall + (size_t)(hb + rc) * DFF + qd * 8;
  }
  const unsigned short* bp[4];
  #pragma unroll
  for (int j = 0; j < 4; ++j)
    bp[j] = W + (size_t)(n0 + wn + 16 * j + lr) * DFF + qd * 8;

  const f32x4 z4 = {0.f, 0.f, 0.f, 0.f};
  f32x4 acc[4][4];
  #pragma unroll
  for (int i = 0; i < 4; ++i)
    #pragma unroll
    for (int j = 0; j < 4; ++j) acc[i][j] = z4;

  #pragma unroll
  for (int k = 0; k < DFF; k += 32) {
    bf16x8 a[4], b[4];
    #pragma unroll
    for (int i = 0; i < 4; ++i) a[i] = *(const bf16x8*)(ap[i] + k);
    #pragma unroll
    for (int j = 0; j < 4; ++j) b[j] = *(const bf16x8*)(bp[j] + k);
    #pragma unroll
    for (int j = 0; j < 4; ++j)
      #pragma unroll
      for (int i = 0; i < 4; ++i) acc[i][j] = MFMA(a[i], b[j], acc[i][j]);
  }

  #pragma unroll
  for (int i = 0; i < 4; ++i) {
    #pragma unroll
    for (int r = 0; r < 4; ++r) {
      const int ent = mt * 128 + wm + 16 * i + qd * 4 + r;
      if (ent < cnt) {
        if (z == 0) {
          float* orow = out + (size_t)ent * DM + n0 + wn;
          #pragma unroll
          for (int j = 0; j < 4; ++j)
            atomicAdd(orow + 16 * j + lr, acc[i][j][r]);
        } else {
          const int   tok = list[(z - 1) * T_TOK + ent];
          const float g   = wgt [(z - 1) * T_TOK + ent];
          float* orow = out + (size_t)tok * DM + n0 + wn;
          #pragma unroll
          for (int j = 0; j < 4; ++j)
            atomicAdd(orow + 16 * j + lr, g * acc[i][j][r]);
        }
      }
    }
  }
}

// ---------------------------------------------------------------------------
extern "C" void kernel_launch(void* const* d_in, const int* in_sizes, int n_in,
                              void* d_out, int out_size, void* d_ws, size_t ws_size,
                              hipStream_t stream) {
  const float* x    = (const float*)d_in[0];
  const float* gw   = (const float*)d_in[1];
  const float* bias = (const float*)d_in[2];
  const float* sgu  = (const float*)d_in[3];
  const float* sdn  = (const float*)d_in[4];
  const float* egu  = (const float*)d_in[5];
  const float* edn  = (const float*)d_in[6];
  float* out = (float*)d_out;

  // workspace layout (bytes)
  char* ws = (char*)d_ws;
  int*            counts = (int*)(ws + 0);        // 16 ints
  int*            list   = (int*)(ws + 64);       // 16*2048 ints
  float*          wgt    = (float*)(ws + 131136); // 16*2048 floats
  unsigned short* Hall   = (unsigned short*)(ws + 262208); // 8192*512 bf16
  // preconverted bf16 copies
  unsigned short* xb   = (unsigned short*)(ws + 8650816);
  unsigned short* sgub = (unsigned short*)(ws + 10747968);
  unsigned short* sdnb = (unsigned short*)(ws + 11796544);
  unsigned short* egub = (unsigned short*)(ws + 12320832);
  unsigned short* ednb = (unsigned short*)(ws + 29098048);
  const size_t need = 37486656;
  if (ws_size < need) return;   // harness provides ~268 MB (measured R2/R4)

  hipMemsetAsync(counts, 0, 64, stream);
  hipMemsetAsync(out, 0, (size_t)out_size * sizeof(float), stream);

  prep_kernel<<<512 + 7040, 256, 0, stream>>>(
      x, gw, bias, counts, list, wgt, sgu, sdn, egu, edn,
      xb, sgub, sdnb, egub, ednb);
  gemm1_fused<<<dim3(4, 16, NE + 1), 256, 0, stream>>>(xb, sgub, egub, Hall, counts, list);
  gemm2_fused<<<dim3(4, 16, NE + 1), 256, 0, stream>>>(Hall, sdnb, ednb, out, counts, list, wgt);
}

// Round 6
// 176.572 us; speedup vs baseline: 1.4602x; 1.4602x over previous
//
#include <hip/hip_runtime.h>

#define T_TOK 2048
#define DM    512
#define DFF   512
#define NE    16
#define LDK   72   // padded LDS row stride (ushorts): 144 B rotates banks by 4/row

typedef __attribute__((ext_vector_type(8))) short bf16x8;
typedef __attribute__((ext_vector_type(4))) float f32x4;
typedef __attribute__((ext_vector_type(8))) unsigned short us8;

__device__ __forceinline__ unsigned short f2bf(float f) {
  unsigned int u = __float_as_uint(f);
  u += 0x7fffu + ((u >> 16) & 1u);   // round-to-nearest-even
  return (unsigned short)(u >> 16);
}

#define MFMA(a,b,c) __builtin_amdgcn_mfma_f32_16x16x32_bf16((a),(b),(c),0,0,0)

// ---------------- prep: blocks 0..511 router, 512+ fp32->bf16 convert ------
__global__ __launch_bounds__(256) void prep_kernel(
    const float* __restrict__ x, const float* __restrict__ gw,
    const float* __restrict__ bias, int* __restrict__ counts,
    int* __restrict__ list, float* __restrict__ wgt,
    const float* __restrict__ sgu, const float* __restrict__ sdn,
    const float* __restrict__ egu, const float* __restrict__ edn,
    unsigned short* __restrict__ xb,   unsigned short* __restrict__ sgub,
    unsigned short* __restrict__ sdnb, unsigned short* __restrict__ egub,
    unsigned short* __restrict__ ednb)
{
  const int tid = threadIdx.x;
  if (blockIdx.x >= 512) {
    // convert: group = 8 elems. x 131072 | sgu 65536 | sdn 32768 | egu 1048576 | edn 524288
    int g = (blockIdx.x - 512) * 256 + tid;
    const float* s; unsigned short* d; int l;
    if      (g <  131072) { s = x;   d = xb;   l = g;           }
    else if (g <  196608) { s = sgu; d = sgub; l = g -  131072; }
    else if (g <  229376) { s = sdn; d = sdnb; l = g -  196608; }
    else if (g < 1277952) { s = egu; d = egub; l = g -  229376; }
    else                  { s = edn; d = ednb; l = g - 1277952; }
    const float* p = s + (size_t)l * 8;
    float4 v0 = *(const float4*)p;
    float4 v1 = *(const float4*)(p + 4);
    us8 o;
    o[0]=f2bf(v0.x); o[1]=f2bf(v0.y); o[2]=f2bf(v0.z); o[3]=f2bf(v0.w);
    o[4]=f2bf(v1.x); o[5]=f2bf(v1.y); o[6]=f2bf(v1.z); o[7]=f2bf(v1.w);
    *(us8*)(d + (size_t)l * 8) = o;
    return;
  }

  // ---- router: one token per wave ----
  __shared__ float lg[4][16];
  __shared__ int bcnt[16], bbase[16];
  __shared__ int sel_s[4][3], pos_s[4][3];
  __shared__ float g_s[4][3];

  const int w = tid >> 6, lane = tid & 63;
  if (tid < 16) bcnt[tid] = 0;
  const int tok = blockIdx.x * 4 + w;
  const int e = lane & 15, part = lane >> 4;

  const float* xr = x + (size_t)tok * DM + part * 128;
  const float* wr = gw + (size_t)e * DM + part * 128;
  float acc = 0.f;
  #pragma unroll 8
  for (int i = 0; i < 128; i += 4) {
    float4 xv = *(const float4*)(xr + i);
    float4 wv = *(const float4*)(wr + i);
    acc += xv.x*wv.x + xv.y*wv.y + xv.z*wv.z + xv.w*wv.w;
  }
  acc += __shfl_xor(acc, 16);
  acc += __shfl_xor(acc, 32);
  if (lane < 16) lg[w][lane] = 1.f / (1.f + __expf(-acc));  // affinity
  __syncthreads();

  if (tid < 4) {
    float aff[16], sc[16];
    #pragma unroll
    for (int i = 0; i < 16; ++i) { aff[i] = lg[tid][i]; sc[i] = aff[i] + bias[i]; }
    int sel[3]; float sa[3]; float sum = 0.f;
    #pragma unroll
    for (int k = 0; k < 3; ++k) {
      float best = -1e30f; int bi = 0;
      for (int i = 0; i < 16; ++i) {
        bool used = false;
        for (int j = 0; j < k; ++j) used |= (sel[j] == i);
        if (!used && sc[i] > best) { best = sc[i]; bi = i; }
      }
      sel[k] = bi; sa[k] = aff[bi]; sum += aff[bi];
    }
    float inv = 1.f / (sum + 1e-9f);
    #pragma unroll
    for (int k = 0; k < 3; ++k) {
      int p = atomicAdd(&bcnt[sel[k]], 1);
      sel_s[tid][k] = sel[k]; pos_s[tid][k] = p; g_s[tid][k] = sa[k] * inv;
    }
  }
  __syncthreads();
  if (tid < 16) bbase[tid] = atomicAdd(&counts[tid], bcnt[tid]);
  __syncthreads();
  if (tid < 4) {
    #pragma unroll
    for (int k = 0; k < 3; ++k) {
      int E = sel_s[tid][k];
      int p = bbase[E] + pos_s[tid][k];
      list[E * T_TOK + p] = blockIdx.x * 4 + tid;
      wgt [E * T_TOK + p] = g_s[tid][k];
    }
  }
}

// ---------------- GEMM1: 64 tok x 64 Hcols per block, 4 waves of 32x32 -----
// z=0 shared expert, z>=1 routed expert z-1. Fused silu(g)*u -> Hall (bf16).
__global__ __launch_bounds__(256, 4) void gemm1_fused(
    const unsigned short* __restrict__ X, const unsigned short* __restrict__ Wsh,
    const unsigned short* __restrict__ Wex, unsigned short* __restrict__ Hall,
    const int* __restrict__ counts, const int* __restrict__ list)
{
  __shared__ unsigned short As[64][LDK];
  __shared__ unsigned short Bg[64][LDK];
  __shared__ unsigned short Bu[64][LDK];

  const int n0 = blockIdx.x * 64;           // H col block
  const int mt = blockIdx.y, z = blockIdx.z;
  int cnt, hb; const unsigned short* W;
  if (z == 0) { cnt = T_TOK; hb = 0; W = Wsh; }
  else {
    const int e = z - 1;
    cnt = counts[e];
    if (mt * 64 >= cnt) return;
    hb = T_TOK;
    for (int i = 0; i < e; ++i) hb += counts[i];
    W = Wex + (size_t)e * (2 * DFF * DM);
  }

  const int tid = threadIdx.x;
  const int sr = tid >> 2;          // staging row 0..63
  const int sc = (tid & 3) * 16;    // staging col base
  const int entry = mt * 64 + sr;
  const bool avalid = entry < cnt;
  const unsigned short* arow = X;
  if (avalid) {
    const int tok = (z == 0) ? entry : list[(z - 1) * T_TOK + entry];
    arow = X + (size_t)tok * DM;
  }
  const unsigned short* grow = W + (size_t)(n0 + sr) * DM;
  const unsigned short* urow = W + (size_t)(DFF + n0 + sr) * DM;

  const int lane = tid & 63;
  const int wm = ((tid >> 6) & 1) * 32;
  const int wn = ((tid >> 7) & 1) * 32;
  const int lr = lane & 15;
  const int qd = lane >> 4;

  const f32x4 z4 = {0.f, 0.f, 0.f, 0.f};
  f32x4 accg[2][2], accu[2][2];
  #pragma unroll
  for (int i = 0; i < 2; ++i)
    #pragma unroll
    for (int j = 0; j < 2; ++j) { accg[i][j] = z4; accu[i][j] = z4; }

  for (int k0 = 0; k0 < DM; k0 += 64) {
    us8 av0 = {0,0,0,0,0,0,0,0}, av1 = {0,0,0,0,0,0,0,0};
    if (avalid) {
      av0 = *(const us8*)(arow + k0 + sc);
      av1 = *(const us8*)(arow + k0 + sc + 8);
    }
    us8 gv0 = *(const us8*)(grow + k0 + sc);
    us8 gv1 = *(const us8*)(grow + k0 + sc + 8);
    us8 uv0 = *(const us8*)(urow + k0 + sc);
    us8 uv1 = *(const us8*)(urow + k0 + sc + 8);
    __syncthreads();
    *(us8*)&As[sr][sc]     = av0; *(us8*)&As[sr][sc + 8] = av1;
    *(us8*)&Bg[sr][sc]     = gv0; *(us8*)&Bg[sr][sc + 8] = gv1;
    *(us8*)&Bu[sr][sc]     = uv0; *(us8*)&Bu[sr][sc + 8] = uv1;
    __syncthreads();
    #pragma unroll
    for (int ks = 0; ks < 2; ++ks) {
      const int kk = ks * 32 + qd * 8;
      bf16x8 a0 = *(const bf16x8*)&As[wm      + lr][kk];
      bf16x8 a1 = *(const bf16x8*)&As[wm + 16 + lr][kk];
      bf16x8 g0 = *(const bf16x8*)&Bg[wn      + lr][kk];
      bf16x8 g1 = *(const bf16x8*)&Bg[wn + 16 + lr][kk];
      bf16x8 u0 = *(const bf16x8*)&Bu[wn      + lr][kk];
      bf16x8 u1 = *(const bf16x8*)&Bu[wn + 16 + lr][kk];
      accg[0][0] = MFMA(a0, g0, accg[0][0]);
      accg[0][1] = MFMA(a0, g1, accg[0][1]);
      accg[1][0] = MFMA(a1, g0, accg[1][0]);
      accg[1][1] = MFMA(a1, g1, accg[1][1]);
      accu[0][0] = MFMA(a0, u0, accu[0][0]);
      accu[0][1] = MFMA(a0, u1, accu[0][1]);
      accu[1][0] = MFMA(a1, u0, accu[1][0]);
      accu[1][1] = MFMA(a1, u1, accu[1][1]);
    }
  }

  #pragma unroll
  for (int sm = 0; sm < 2; ++sm)
    #pragma unroll
    for (int sn = 0; sn < 2; ++sn) {
      const int col = n0 + wn + sn * 16 + lr;
      #pragma unroll
      for (int r = 0; r < 4; ++r) {
        const int ent = mt * 64 + wm + sm * 16 + qd * 4 + r;
        if (ent < cnt) {
          float g = accg[sm][sn][r];
          float u = accu[sm][sn][r];
          float h = (g / (1.f + __expf(-g))) * u;   // silu(g)*u
          Hall[(size_t)(hb + ent) * DFF + col] = f2bf(h);
        }
      }
    }
}

// ---------------- GEMM2: 64 tok x 64 out-cols per block --------------------
__global__ __launch_bounds__(256, 4) void gemm2_fused(
    const unsigned short* __restrict__ Hall, const unsigned short* __restrict__ Wsh,
    const unsigned short* __restrict__ Wex, float* __restrict__ out,
    const int* __restrict__ counts, const int* __restrict__ list,
    const float* __restrict__ wgt)
{
  __shared__ unsigned short Ah[64][LDK];
  __shared__ unsigned short Bd[64][LDK];

  const int n0 = blockIdx.x * 64;           // out col block
  const int mt = blockIdx.y, z = blockIdx.z;
  int cnt, hb; const unsigned short* W;
  if (z == 0) { cnt = T_TOK; hb = 0; W = Wsh; }
  else {
    const int e = z - 1;
    cnt = counts[e];
    if (mt * 64 >= cnt) return;
    hb = T_TOK;
    for (int i = 0; i < e; ++i) hb += counts[i];
    W = Wex + (size_t)e * (DM * DFF);
  }

  const int tid = threadIdx.x;
  const int sr = tid >> 2;
  const int sc = (tid & 3) * 16;
  const int entry = mt * 64 + sr;
  const bool avalid = entry < cnt;
  const unsigned short* arow = Hall;
  if (avalid) arow = Hall + (size_t)(hb + entry) * DFF;
  const unsigned short* drow = W + (size_t)(n0 + sr) * DFF;

  const int lane = tid & 63;
  const int wm = ((tid >> 6) & 1) * 32;
  const int wn = ((tid >> 7) & 1) * 32;
  const int lr = lane & 15;
  const int qd = lane >> 4;

  const f32x4 z4 = {0.f, 0.f, 0.f, 0.f};
  f32x4 acc[2][2];
  #pragma unroll
  for (int i = 0; i < 2; ++i)
    #pragma unroll
    for (int j = 0; j < 2; ++j) acc[i][j] = z4;

  for (int k0 = 0; k0 < DFF; k0 += 64) {
    us8 av0 = {0,0,0,0,0,0,0,0}, av1 = {0,0,0,0,0,0,0,0};
    if (avalid) {
      av0 = *(const us8*)(arow + k0 + sc);
      av1 = *(const us8*)(arow + k0 + sc + 8);
    }
    us8 dv0 = *(const us8*)(drow + k0 + sc);
    us8 dv1 = *(const us8*)(drow + k0 + sc + 8);
    __syncthreads();
    *(us8*)&Ah[sr][sc]     = av0; *(us8*)&Ah[sr][sc + 8] = av1;
    *(us8*)&Bd[sr][sc]     = dv0; *(us8*)&Bd[sr][sc + 8] = dv1;
    __syncthreads();
    #pragma unroll
    for (int ks = 0; ks < 2; ++ks) {
      const int kk = ks * 32 + qd * 8;
      bf16x8 a0 = *(const bf16x8*)&Ah[wm      + lr][kk];
      bf16x8 a1 = *(const bf16x8*)&Ah[wm + 16 + lr][kk];
      bf16x8 b0 = *(const bf16x8*)&Bd[wn      + lr][kk];
      bf16x8 b1 = *(const bf16x8*)&Bd[wn + 16 + lr][kk];
      acc[0][0] = MFMA(a0, b0, acc[0][0]);
      acc[0][1] = MFMA(a0, b1, acc[0][1]);
      acc[1][0] = MFMA(a1, b0, acc[1][0]);
      acc[1][1] = MFMA(a1, b1, acc[1][1]);
    }
  }

  #pragma unroll
  for (int sm = 0; sm < 2; ++sm)
    #pragma unroll
    for (int sn = 0; sn < 2; ++sn) {
      const int col = n0 + wn + sn * 16 + lr;
      #pragma unroll
      for (int r = 0; r < 4; ++r) {
        const int ent = mt * 64 + wm + sm * 16 + qd * 4 + r;
        if (ent < cnt) {
          float v = acc[sm][sn][r];
          if (z == 0) {
            atomicAdd(out + (size_t)ent * DM + col, v);
          } else {
            const int   tok = list[(z - 1) * T_TOK + ent];
            const float g   = wgt [(z - 1) * T_TOK + ent];
            atomicAdd(out + (size_t)tok * DM + col, g * v);
          }
        }
      }
    }
}

// ---------------------------------------------------------------------------
extern "C" void kernel_launch(void* const* d_in, const int* in_sizes, int n_in,
                              void* d_out, int out_size, void* d_ws, size_t ws_size,
                              hipStream_t stream) {
  const float* x    = (const float*)d_in[0];
  const float* gw   = (const float*)d_in[1];
  const float* bias = (const float*)d_in[2];
  const float* sgu  = (const float*)d_in[3];
  const float* sdn  = (const float*)d_in[4];
  const float* egu  = (const float*)d_in[5];
  const float* edn  = (const float*)d_in[6];
  float* out = (float*)d_out;

  // workspace layout (bytes)
  char* ws = (char*)d_ws;
  int*            counts = (int*)(ws + 0);        // 16 ints
  int*            list   = (int*)(ws + 64);       // 16*2048 ints
  float*          wgt    = (float*)(ws + 131136); // 16*2048 floats
  unsigned short* Hall   = (unsigned short*)(ws + 262208); // 8192*512 bf16
  // preconverted bf16 copies
  unsigned short* xb   = (unsigned short*)(ws + 8650816);
  unsigned short* sgub = (unsigned short*)(ws + 10747968);
  unsigned short* sdnb = (unsigned short*)(ws + 11796544);
  unsigned short* egub = (unsigned short*)(ws + 12320832);
  unsigned short* ednb = (unsigned short*)(ws + 29098048);
  const size_t need = 37486656;
  if (ws_size < need) return;   // harness provides ~268 MB (measured R2/R4)

  hipMemsetAsync(counts, 0, 64, stream);
  hipMemsetAsync(out, 0, (size_t)out_size * sizeof(float), stream);

  prep_kernel<<<512 + 7040, 256, 0, stream>>>(
      x, gw, bias, counts, list, wgt, sgu, sdn, egu, edn,
      xb, sgub, sdnb, egub, ednb);
  gemm1_fused<<<dim3(8, 32, NE + 1), 256, 0, stream>>>(xb, sgub, egub, Hall, counts, list);
  gemm2_fused<<<dim3(8, 32, NE + 1), 256, 0, stream>>>(Hall, sdnb, ednb, out, counts, list, wgt);
}